// Round 1
// baseline (92.403 us; speedup 1.0000x reference)
//
#include <hip/hip_runtime.h>

// TimeEmbedding: out[i, e] = W[e, elt[i]] + b[e]
//   elt: [B] int32, W: [E, V] f32 row-major, b: [E] f32, out: [B, E] f32
//   B = 4096, E = 128, V = 100000.
//
// R2 theory: the gather is DRAM-random-bound (~1.4 TB/s effective; every timed
// iteration is L3-cold because the harness's 256 MiB workspace poison flushes
// the Infinity Cache). Fix = issue the line fetches in ascending-address order:
//   K1: single-block bucket sort of (v, i) pairs by v>>7 (782 buckets of 128
//       values = 4 cache lines; within-bucket order irrelevant for coalescing).
//   K2: wave lanes = 64 consecutive sorted pairs, 8 e's per thread. Mean sorted
//       gap = 24.4 values = 98 B < one line -> each 64-lane load merges to
//       ~10-50 SEQUENTIAL lines; shared lines fetched once (~37 MB total,
//       near-streaming DRAM order vs ~50-67 MB fully random before).
// Arithmetic identical to R1 (w + b in f32) -> bitwise-equal output.

#define EMB_DIM 128
#define NB_WORDS 100000
#define BATCH 4096
#define NBUCK 1024   // 782 used (v>>7, v < 100000), padded to pow2 for the scan

__global__ __launch_bounds__(1024) void bucket_sort_kernel(
    const int* __restrict__ elt,
    int2* __restrict__ sorted)
{
    __shared__ int hist[NBUCK];
    __shared__ int base[NBUCK];
    const int t = threadIdx.x;

    hist[t] = 0;
    __syncthreads();

    int v[4];
    #pragma unroll
    for (int j = 0; j < 4; ++j) {
        v[j] = elt[j * 1024 + t];            // coalesced
        atomicAdd(&hist[v[j] >> 7], 1);      // ~5.2 entries/bucket: low contention
    }
    __syncthreads();

    // Hillis-Steele inclusive scan over 1024 buckets
    const int own = hist[t];
    for (int d = 1; d < NBUCK; d <<= 1) {
        const int x = (t >= d) ? hist[t - d] : 0;
        __syncthreads();
        hist[t] += x;
        __syncthreads();
    }
    base[t] = hist[t] - own;                 // exclusive prefix
    __syncthreads();

    #pragma unroll
    for (int j = 0; j < 4; ++j) {
        const int p = atomicAdd(&base[v[j] >> 7], 1);
        sorted[p] = make_int2(v[j], j * 1024 + t);   // (value, batch index)
    }
}

// Grid: 256 blocks x 256 threads = 65536 threads; each handles 8 e's for one
// sorted pair. blockIdx = c*4 + bsub: c = 64-pair chunk, bsub = e-range of 32.
// Each 128 B out-line (i, e in [32*bsub, 32*bsub+32)) is written entirely by
// one block -> full-line L2 writebacks.
__global__ __launch_bounds__(256) void gather_kernel(
    const int2* __restrict__ sorted,
    const float* __restrict__ W,
    const float* __restrict__ b,
    float* __restrict__ out)
{
    const int w    = threadIdx.x >> 6;       // wave in block (0..3)
    const int lane = threadIdx.x & 63;
    const int bsub = blockIdx.x & 3;         // e-subrange
    const int c    = blockIdx.x >> 2;        // pair chunk (0..63)

    const int q  = bsub * 4 + w;             // 0..15
    const int e0 = q * 8;                    // thread's 8 consecutive e's

    const int2 vi = sorted[c * 64 + lane];   // lane = consecutive sorted pairs
    const int v = vi.x;
    const int i = vi.y;

    // 8 independent gathers; within a wave each load instruction hits ~10-50
    // sequential 128 B lines (sorted v window ~1.5 KB), merged by the coalescer.
    const float* Wp = W + (size_t)e0 * NB_WORDS + v;
    float wv[8];
    #pragma unroll
    for (int j = 0; j < 8; ++j) wv[j] = Wp[(size_t)j * NB_WORDS];

    const float4 b0 = ((const float4*)b)[q * 2];
    const float4 b1 = ((const float4*)b)[q * 2 + 1];

    float4 r0, r1;
    r0.x = wv[0] + b0.x; r0.y = wv[1] + b0.y; r0.z = wv[2] + b0.z; r0.w = wv[3] + b0.w;
    r1.x = wv[4] + b1.x; r1.y = wv[5] + b1.y; r1.z = wv[6] + b1.z; r1.w = wv[7] + b1.w;

    float4* op = (float4*)out + (size_t)i * 32 + q * 2;
    op[0] = r0;
    op[1] = r1;
}

extern "C" void kernel_launch(void* const* d_in, const int* in_sizes, int n_in,
                              void* d_out, int out_size, void* d_ws, size_t ws_size,
                              hipStream_t stream) {
    const int*   elt = (const int*)d_in[0];
    const float* W   = (const float*)d_in[1];
    const float* b   = (const float*)d_in[2];
    float*       out = (float*)d_out;

    int2* sorted = (int2*)d_ws;              // 4096 * 8 B = 32 KB of workspace

    bucket_sort_kernel<<<1, 1024, 0, stream>>>(elt, sorted);

    const int grid = (BATCH / 64) * 4;       // 256 blocks
    gather_kernel<<<grid, 256, 0, stream>>>(sorted, W, b, out);
}

// Round 2
// 89.719 us; speedup vs baseline: 1.0299x; 1.0299x over previous
//
#include <hip/hip_runtime.h>
#include <hip/hip_bf16.h>

// TimeEmbedding: out[i, e] = W[e, elt[i]] + b[e]
//   elt: [B]    int32, values in [0, V)
//   W:   [E, V] float32 (row-major, W[e, v] = W[e*V + v])
//   b:   [E]    float32
//   out: [B, E] float32
// B = 4096, E = 128, V = 100000.
//
// R3 = revert to R1 (harness-verified 89.96 us).
// Post-mortem of R2 (bucket-sort + sorted gather, 92.40 us):
//   - dur_us ~= 2 x 43 us of harness 256 MiB poison fills + kernel.
//     The gather kernel never appears in top-5 (>42 us would) -> it is ~4 us.
//   - At ~4 us for 524288 gathered elements, W is L3-resident (the memory-side
//     Infinity Cache is not evicted by the streaming poison fill). The gather
//     is at the L3 random-access floor; DRAM row-locality sorting solved a
//     non-problem and its serial single-block cost (+2.4 us) was pure loss.
// R1 structure: each thread handles 4 consecutive e for one i:
//   - 4 independent strided gather loads from W (ILP=4, latency overlap)
//   - one coalesced float4 store to out, float4 bias load
//   - 32 lanes share one elt[i] load -> 1 request, broadcast

#define EMB_DIM 128
#define NB_WORDS 100000
#define BATCH 4096

__global__ __launch_bounds__(256) void time_embedding_kernel(
    const int* __restrict__ elt,
    const float* __restrict__ W,
    const float* __restrict__ b,
    float* __restrict__ out)
{
    // tid over B * (E/4) = 4096 * 32 = 131072
    const int tid = blockIdx.x * blockDim.x + threadIdx.x;
    const int q = tid & 31;          // which float4 of the row (0..31)
    const int i = tid >> 5;          // batch index
    const int e = q << 2;            // starting embedding dim (0,4,...,124)

    const int v = elt[i];            // 32 lanes share this address -> 1 request

    const size_t base = (size_t)e * NB_WORDS + v;
    // 4 independent gathers, stride NB_WORDS floats (400 KB) apart
    const float w0 = W[base];
    const float w1 = W[base + (size_t)NB_WORDS];
    const float w2 = W[base + (size_t)2 * NB_WORDS];
    const float w3 = W[base + (size_t)3 * NB_WORDS];

    const float4 bb = ((const float4*)b)[q];

    float4 r;
    r.x = w0 + bb.x;
    r.y = w1 + bb.y;
    r.z = w2 + bb.z;
    r.w = w3 + bb.w;

    ((float4*)out)[(size_t)i * 32 + q] = r;   // coalesced 16 B/lane store
}

extern "C" void kernel_launch(void* const* d_in, const int* in_sizes, int n_in,
                              void* d_out, int out_size, void* d_ws, size_t ws_size,
                              hipStream_t stream) {
    const int*   elt = (const int*)d_in[0];
    const float* W   = (const float*)d_in[1];
    const float* b   = (const float*)d_in[2];
    float*       out = (float*)d_out;

    const int total = BATCH * (EMB_DIM / 4);        // 131072 threads
    const int block = 256;
    const int grid  = (total + block - 1) / block;  // 512 blocks
    time_embedding_kernel<<<grid, block, 0, stream>>>(elt, W, b, out);
}